// Round 9
// baseline (222.008 us; speedup 1.0000x reference)
//
#include <hip/hip_runtime.h>
#include <hip/hip_bf16.h>

typedef __bf16 bf16_t;
typedef __attribute__((ext_vector_type(8))) __bf16 bf16x8;
typedef __attribute__((ext_vector_type(4))) __bf16 bf16x4;
typedef __attribute__((ext_vector_type(4))) float f32x4;

// Problem constants
// B=2, N=2048, D=256, H=8, M=2, NN=2048, K=8, dh=32

static __device__ __forceinline__ unsigned pk2(float x, float y) {
    unsigned short ux = __builtin_bit_cast(unsigned short, (bf16_t)x);
    unsigned short uy = __builtin_bit_cast(unsigned short, (bf16_t)y);
    return (unsigned)ux | ((unsigned)uy << 16);
}

// ---------------------------------------------------------------------------
// Kernel 0: convert weights to bf16
// ---------------------------------------------------------------------------
__global__ __launch_bounds__(256) void wconv_kernel(const float* __restrict__ w_in,
                                                    const float* __restrict__ w_out,
                                                    bf16_t* __restrict__ w_in_b,
                                                    bf16_t* __restrict__ w_out_b) {
    int i = blockIdx.x * 256 + threadIdx.x;
    if (i < 768 * 256) w_in_b[i] = (bf16_t)w_in[i];
    if (i < 256 * 256) w_out_b[i] = (bf16_t)w_out[i];
}

// ---------------------------------------------------------------------------
// Kernel 1: KNN top-8, one WAVE per query. (unchanged, proven)
// ---------------------------------------------------------------------------
__global__ __launch_bounds__(1024) void knn_kernel(const float* __restrict__ cur_pts,
                                                   const float* __restrict__ nbr_pts,
                                                   int* __restrict__ idx_out) {
    int p = blockIdx.y;  // 0..5 : 0,1 = current batches; 2..5 = (m*2+b)
    const float* pts = (p < 2) ? (cur_pts + (size_t)p * 2048 * 3)
                               : (nbr_pts + (size_t)(p - 2) * 2048 * 3);

    __shared__ __align__(16) float4 spts[2048];

    int tid = threadIdx.x;
    for (int i = tid; i < 2048; i += 1024) {
        float x = pts[i * 3 + 0], y = pts[i * 3 + 1], z = pts[i * 3 + 2];
        float sq = __fadd_rn(__fadd_rn(__fmul_rn(x, x), __fmul_rn(y, y)), __fmul_rn(z, z));
        spts[i] = make_float4(x, y, z, sq);
    }
    __syncthreads();

    int wave = tid >> 6, lane = tid & 63;
    int q = blockIdx.x * 16 + wave;
    float4 qp4 = spts[q];

    float dist[8];
    int di[8];
#pragma unroll
    for (int r = 0; r < 8; r++) { dist[r] = 3.4e38f; di[r] = 0x7fffffff; }

    for (int t = 0; t < 32; t++) {
        int j = t * 64 + lane;
        float4 pp = spts[j];
        float dot = __fadd_rn(__fadd_rn(__fmul_rn(qp4.x, pp.x), __fmul_rn(qp4.y, pp.y)),
                              __fmul_rn(qp4.z, pp.z));
        float d2 = __fsub_rn(__fadd_rn(qp4.w, pp.w), __fmul_rn(2.0f, dot));
        if (d2 < dist[7]) {
#pragma unroll
            for (int r = 7; r >= 1; --r) {
                bool cm = d2 < dist[r - 1];
                bool cr = d2 < dist[r];
                float nd = cm ? dist[r - 1] : (cr ? d2 : dist[r]);
                int ni = cm ? di[r - 1] : (cr ? j : di[r]);
                dist[r] = nd; di[r] = ni;
            }
            if (d2 < dist[0]) { dist[0] = d2; di[0] = j; }
        }
    }

    int res[8];
#pragma unroll
    for (int r = 0; r < 8; r++) {
        float bd = dist[0];
        int bi = di[0];
#pragma unroll
        for (int m = 1; m < 64; m <<= 1) {
            float od = __shfl_xor(bd, m);
            int oi = __shfl_xor(bi, m);
            if (od < bd || (od == bd && oi < bi)) { bd = od; bi = oi; }
        }
        res[r] = bi;
        bool win = (di[0] == bi);
#pragma unroll
        for (int k = 0; k < 7; k++) {
            dist[k] = win ? dist[k + 1] : dist[k];
            di[k]   = win ? di[k + 1]   : di[k];
        }
        if (win) { dist[7] = 3.4e38f; di[7] = 0x7fffffff; }
    }

    if (lane == 0) {
        int4* o = (int4*)(idx_out + ((size_t)p * 2048 + q) * 8);
        o[0] = make_int4(res[0], res[1], res[2], res[3]);
        o[1] = make_int4(res[4], res[5], res[6], res[7]);
    }
}

// ---------------------------------------------------------------------------
// Kernel 2: gather neighbor features, edge = f - mean(nbr). (unchanged)
// ---------------------------------------------------------------------------
__global__ __launch_bounds__(64) void edge_kernel(const float* __restrict__ cur_feat,
                                                  const float* __restrict__ nbr_feat,
                                                  const int* __restrict__ idx_buf,
                                                  bf16_t* __restrict__ cur_edge,
                                                  bf16_t* __restrict__ all_nbr) {
    int blk = blockIdx.x;
    int p = blk >> 11, q = blk & 2047;
    const float* feat;
    bf16_t* outp;
    if (p < 2) {
        feat = cur_feat + (size_t)p * 2048 * 256;
        outp = cur_edge + ((size_t)p * 2048 + q) * 256;
    } else {
        int mb = p - 2;
        int m = mb >> 1, bb = mb & 1;
        feat = nbr_feat + (size_t)mb * 2048 * 256;
        outp = all_nbr + ((size_t)bb * 4096 + m * 2048 + q) * 256;
    }
    const int* idx = idx_buf + ((size_t)p * 2048 + q) * 8;
    int t = threadIdx.x;
    float4 self = ((const float4*)(feat + (size_t)q * 256))[t];
    float sx = 0.f, sy = 0.f, sz = 0.f, sw = 0.f;
#pragma unroll
    for (int r = 0; r < 8; r++) {
        float4 f = ((const float4*)(feat + (size_t)idx[r] * 256))[t];
        sx += f.x; sy += f.y; sz += f.z; sw += f.w;
    }
    bf16x4 v;
    v[0] = (bf16_t)(self.x - sx * 0.125f);
    v[1] = (bf16_t)(self.y - sy * 0.125f);
    v[2] = (bf16_t)(self.z - sz * 0.125f);
    v[3] = (bf16_t)(self.w - sw * 0.125f);
    *(bf16x4*)(outp + 4 * t) = v;
}

// ---------------------------------------------------------------------------
// Kernel 3: QKV projections via bf16 MFMA. z=0: qp (scaled), z=1: kp,
// z=2: vp ROW-major [b*4096+kv][256] (coalesced; the old direct-transposed
// write was 2M x 2B stores at 8KB stride). vt_kernel transposes after.
// ---------------------------------------------------------------------------
__global__ __launch_bounds__(256) void qkv_kernel(const bf16_t* __restrict__ cur_edge,
                                                  const bf16_t* __restrict__ all_nbr,
                                                  const bf16_t* __restrict__ w_in,
                                                  const float* __restrict__ b_in,
                                                  bf16_t* __restrict__ qp,
                                                  bf16_t* __restrict__ kp,
                                                  bf16_t* __restrict__ vp) {
    int z = blockIdx.z;
    int Mrows = (z == 0) ? 4096 : 8192;
    int m0base = blockIdx.y * 64;
    if (m0base >= Mrows) return;
    const bf16_t* A = (z == 0) ? cur_edge : all_nbr;
    const bf16_t* W = w_in + (size_t)z * 256 * 256;

    int wave = threadIdx.x >> 6, lane = threadIdx.x & 63;
    int wr = wave >> 1, wc = wave & 1;
    int m0 = m0base + wr * 32;
    int n0 = blockIdx.x * 64 + wc * 32;
    int lr = lane & 15, lg = lane >> 4;

    f32x4 acc[2][2] = {};
    for (int kc = 0; kc < 256; kc += 32) {
        bf16x8 a[2], b[2];
#pragma unroll
        for (int i = 0; i < 2; i++)
            a[i] = *(const bf16x8*)(A + (size_t)(m0 + i * 16 + lr) * 256 + kc + lg * 8);
#pragma unroll
        for (int i = 0; i < 2; i++)
            b[i] = *(const bf16x8*)(W + (size_t)(n0 + i * 16 + lr) * 256 + kc + lg * 8);
#pragma unroll
        for (int i = 0; i < 2; i++)
#pragma unroll
            for (int j = 0; j < 2; j++)
                acc[i][j] = __builtin_amdgcn_mfma_f32_16x16x32_bf16(a[i], b[j], acc[i][j], 0, 0, 0);
    }

    const float inv_s = 0.17677669529663687f;  // 1/sqrt(32)
#pragma unroll
    for (int i = 0; i < 2; i++)
#pragma unroll
        for (int j = 0; j < 2; j++)
#pragma unroll
            for (int r = 0; r < 4; r++) {
                int mm = m0 + i * 16 + lg * 4 + r;
                int nn = n0 + j * 16 + lr;
                float v = acc[i][j][r] + b_in[z * 256 + nn];
                if (z == 0) {
                    qp[(size_t)mm * 256 + nn] = (bf16_t)(v * inv_s);
                } else if (z == 1) {
                    kp[(size_t)mm * 256 + nn] = (bf16_t)v;
                } else {
                    vp[(size_t)mm * 256 + nn] = (bf16_t)v;
                }
            }
}

// ---------------------------------------------------------------------------
// Kernel 3b: transpose vp [b,4096kv][8h*32dd] -> vpT [b,h,32dd][4096kv]
// via padded LDS tile; both global sides coalesced (64B/128B segments).
// ---------------------------------------------------------------------------
__global__ __launch_bounds__(256) void vt_kernel(const bf16_t* __restrict__ vp,
                                                 bf16_t* __restrict__ vpT) {
    int kc = blockIdx.x;          // kv chunk of 64 (0..63)
    int bh = blockIdx.y;          // 0..15
    int b = bh >> 3, h = bh & 7;
    __shared__ bf16_t tile[64][34];
    int tid = threadIdx.x;

    const bf16_t* src = vp + ((size_t)b * 4096 + kc * 64) * 256 + h * 32;
    int dd0 = (tid & 7) * 4, kvr = tid >> 3;          // 32 kv rows per pass
#pragma unroll
    for (int it = 0; it < 2; it++) {
        int kv = it * 32 + kvr;
        bf16x4 v = *(const bf16x4*)(src + (size_t)kv * 256 + dd0);
#pragma unroll
        for (int j = 0; j < 4; j++) tile[kv][dd0 + j] = v[j];
    }
    __syncthreads();

    bf16_t* dst = vpT + (((size_t)b * 8 + h) * 32) * 4096 + kc * 64;
    int kv0 = (tid & 15) * 4, ddr0 = tid >> 4;        // 16 dd rows per pass
#pragma unroll
    for (int it = 0; it < 2; it++) {
        int dd = it * 16 + ddr0;
        bf16x4 v;
#pragma unroll
        for (int j = 0; j < 4; j++) v[j] = tile[kv0 + j][dd];
        *(bf16x4*)(dst + (size_t)dd * 4096 + kv0) = v;
    }
}

// ---------------------------------------------------------------------------
// Kernel 4: cross attention, kv-SPLIT (c=4), WAVE-INDEPENDENT (no barriers,
// no K/V staging): previous rounds proved the kernel is LDS-throughput-bound
// (op-count arithmetic matched 48µs), so this cuts LDS ops ~8x:
//   - K/V frags loaded directly from global (XCD swizzle -> L2-resident).
//   - SWAPPED QK^T: s = mfma(K, Q) puts kv-adjacent P values in adjacent
//     regs -> P written as 4 ds_write_b64/tile (packed bf16 pairs) instead
//     of 16 scalar b16. Layout byte(q,kv) = q*64 + ((kv>>3)^(q&3))*16 +
//     (kv&7)*2: write = ideal 4 dwords/bank, read b128 conflict-free,
//     verified symbolically + spot (q=5,kv=19).
//   - lsum: per-lane over kv, shfl_xor(16,32) reduce; Lpart from lg==0.
//   - 32 q rows/wave, grid 1024 XCD-swizzled (4 blocks/CU, 4 waves/SIMD).
// ---------------------------------------------------------------------------
__global__ __launch_bounds__(256, 4) void attn_kernel(const bf16_t* __restrict__ qp,
                                                      const bf16_t* __restrict__ kp,
                                                      const bf16_t* __restrict__ vpT,
                                                      bf16_t* __restrict__ Opart,
                                                      float* __restrict__ Lpart) {
    int d = blockIdx.x;
    int xcd = d & 7, j = d >> 3;
    int xb = j & 15;                  // q-tile (128 q each)
    int g = xcd + 8 * (j >> 4);       // 0..63, contiguous per XCD
    int bh = g & 15, c = g >> 4;
    int b = bh >> 3, h = bh & 7;

    int wave = threadIdx.x >> 6, lane = threadIdx.x & 63;
    int lr = lane & 15, lg = lane >> 4;
    int q0 = xb * 128 + wave * 32;

    const bf16_t* Qb = qp + ((size_t)b * 2048 + q0) * 256 + h * 32;
    const bf16_t* Kb = kp + (size_t)b * 4096 * 256 + h * 32;
    const bf16_t* Vb = vpT + ((size_t)b * 8 + h) * 32 * 4096;

    // per-wave P tile: 32q x 32kv bf16 = 2KB, swizzled layout (see header)
    __shared__ __align__(16) char P_lds[4][2048];
    char* Pw = &P_lds[wave][0];

    bf16x8 qf[2];
    qf[0] = *(const bf16x8*)(Qb + (size_t)lr * 256 + lg * 8);
    qf[1] = *(const bf16x8*)(Qb + (size_t)(16 + lr) * 256 + lg * 8);

    f32x4 oacc[2][2] = {};
    float lsum[2] = {0.f, 0.f};
    const f32x4 zf = {0.f, 0.f, 0.f, 0.f};

    // P write/read byte offsets (compile-time-ish, per lane)
    int wb[2][2], rb[2];
#pragma unroll
    for (int ms = 0; ms < 2; ms++) {
        rb[ms] = (ms * 16 + lr) * 64 + ((lg ^ (lr & 3)) << 4);
#pragma unroll
        for (int kvs = 0; kvs < 2; kvs++)
            wb[ms][kvs] = (ms * 16 + lr) * 64 +
                          (((kvs * 2 + (lg >> 1)) ^ (lr & 3)) << 4) + ((lg & 1) << 3);
    }

    int kv_lo = c * 1024;
    for (int t = 0; t < 32; t++) {
        int kv0 = kv_lo + t * 32;
        bf16x8 kf0 = *(const bf16x8*)(Kb + (size_t)(kv0 + lr) * 256 + lg * 8);
        bf16x8 kf1 = *(const bf16x8*)(Kb + (size_t)(kv0 + 16 + lr) * 256 + lg * 8);
        bf16x8 vf0 = *(const bf16x8*)(Vb + (size_t)lr * 4096 + kv0 + lg * 8);
        bf16x8 vf1 = *(const bf16x8*)(Vb + (size_t)(16 + lr) * 4096 + kv0 + lg * 8);

#pragma unroll
        for (int ms = 0; ms < 2; ms++) {
            // swapped: A=K rows=kv, B=Q cols=q -> lane holds (q=ms*16+lr, kv=kvs*16+lg*4+r)
            f32x4 s0 = __builtin_amdgcn_mfma_f32_16x16x32_bf16(kf0, qf[ms], zf, 0, 0, 0);
            f32x4 s1 = __builtin_amdgcn_mfma_f32_16x16x32_bf16(kf1, qf[ms], zf, 0, 0, 0);
            float p00 = __expf(s0[0]), p01 = __expf(s0[1]);
            float p02 = __expf(s0[2]), p03 = __expf(s0[3]);
            float p10 = __expf(s1[0]), p11 = __expf(s1[1]);
            float p12 = __expf(s1[2]), p13 = __expf(s1[3]);
            lsum[ms] += (p00 + p01) + (p02 + p03) + (p10 + p11) + (p12 + p13);
            uint2 w0, w1;
            w0.x = pk2(p00, p01); w0.y = pk2(p02, p03);
            w1.x = pk2(p10, p11); w1.y = pk2(p12, p13);
            *(uint2*)(Pw + wb[ms][0]) = w0;
            *(uint2*)(Pw + wb[ms][1]) = w1;
        }

#pragma unroll
        for (int ms = 0; ms < 2; ms++) {
            bf16x8 pf = *(const bf16x8*)(Pw + rb[ms]);
            oacc[ms][0] = __builtin_amdgcn_mfma_f32_16x16x32_bf16(pf, vf0, oacc[ms][0], 0, 0, 0);
            oacc[ms][1] = __builtin_amdgcn_mfma_f32_16x16x32_bf16(pf, vf1, oacc[ms][1], 0, 0, 0);
        }
    }

    // lsum currently: partial over this lane's 8 kv slots; reduce over lg groups
#pragma unroll
    for (int ms = 0; ms < 2; ms++) {
        float s = lsum[ms];
        s += __shfl_xor(s, 16);
        s += __shfl_xor(s, 32);
        lsum[ms] = s;  // full row-sum for q = q0 + ms*16 + lr
    }

    if (lg == 0) {
        Lpart[(((size_t)c * 2 + b) * 8 + h) * 2048 + q0 + lr] = lsum[0];
        Lpart[(((size_t)c * 2 + b) * 8 + h) * 2048 + q0 + 16 + lr] = lsum[1];
    }

#pragma unroll
    for (int ms = 0; ms < 2; ms++)
#pragma unroll
        for (int r = 0; r < 4; r++) {
            int qq = q0 + ms * 16 + lg * 4 + r;
#pragma unroll
            for (int ds = 0; ds < 2; ds++) {
                int dd = h * 32 + ds * 16 + lr;
                Opart[(((size_t)c * 2 + b) * 2048 + qq) * 256 + dd] = (bf16_t)oacc[ms][ds][r];
            }
        }
}

// ---------------------------------------------------------------------------
// Kernel 4b: combine kv-split partials: o = (sum_c O_c) / (sum_c l_c).
// ---------------------------------------------------------------------------
__global__ __launch_bounds__(256) void attn_combine(const bf16_t* __restrict__ Opart,
                                                    const float* __restrict__ Lpart,
                                                    bf16_t* __restrict__ o_buf) {
    int t = blockIdx.x * 256 + threadIdx.x;  // 0..131071
    int row = t >> 5;            // 0..4095  (b*2048+q)
    int c8 = (t & 31) * 8;       // col start, all 8 cols share one head
    int b = row >> 11, q = row & 2047, h = c8 >> 5;

    float acc[8] = {};
    float l = 0.f;
#pragma unroll
    for (int c = 0; c < 4; c++) {
        bf16x8 v = *(const bf16x8*)(Opart + (((size_t)c * 2 + b) * 2048 + q) * 256 + c8);
#pragma unroll
        for (int j = 0; j < 8; j++) acc[j] += (float)v[j];
        l += Lpart[(((size_t)c * 2 + b) * 8 + h) * 2048 + q];
    }
    float rl = 1.0f / l;
    bf16x8 o;
#pragma unroll
    for (int j = 0; j < 8; j++) o[j] = (bf16_t)(acc[j] * rl);
    *(bf16x8*)(o_buf + (size_t)row * 256 + c8) = o;
}

// ---------------------------------------------------------------------------
// Kernel 5: out = o @ out_w^T + out_b + points @ spatial_w^T + spatial_b
// ---------------------------------------------------------------------------
__global__ __launch_bounds__(256) void outproj_kernel(const bf16_t* __restrict__ o_buf,
                                                      const bf16_t* __restrict__ w_out,
                                                      const float* __restrict__ b_out,
                                                      const float* __restrict__ cur_pts,
                                                      const float* __restrict__ sw,
                                                      const float* __restrict__ sb,
                                                      float* __restrict__ out) {
    int wave = threadIdx.x >> 6, lane = threadIdx.x & 63;
    int wr = wave >> 1, wc = wave & 1;
    int m0 = blockIdx.y * 64 + wr * 32;
    int n0 = blockIdx.x * 64 + wc * 32;
    int lr = lane & 15, lg = lane >> 4;

    f32x4 acc[2][2] = {};
    for (int kc = 0; kc < 256; kc += 32) {
        bf16x8 a[2], b[2];
#pragma unroll
        for (int i = 0; i < 2; i++)
            a[i] = *(const bf16x8*)(o_buf + (size_t)(m0 + i * 16 + lr) * 256 + kc + lg * 8);
#pragma unroll
        for (int i = 0; i < 2; i++)
            b[i] = *(const bf16x8*)(w_out + (size_t)(n0 + i * 16 + lr) * 256 + kc + lg * 8);
#pragma unroll
        for (int i = 0; i < 2; i++)
#pragma unroll
            for (int j = 0; j < 2; j++)
                acc[i][j] = __builtin_amdgcn_mfma_f32_16x16x32_bf16(a[i], b[j], acc[i][j], 0, 0, 0);
    }

#pragma unroll
    for (int i = 0; i < 2; i++)
#pragma unroll
        for (int j = 0; j < 2; j++)
#pragma unroll
            for (int r = 0; r < 4; r++) {
                int mm = m0 + i * 16 + lg * 4 + r;
                int nn = n0 + j * 16 + lr;
                const float* pp = cur_pts + (size_t)mm * 3;
                float sp = pp[0] * sw[nn * 3 + 0] + pp[1] * sw[nn * 3 + 1] + pp[2] * sw[nn * 3 + 2] + sb[nn];
                out[(size_t)mm * 256 + nn] = acc[i][j][r] + b_out[nn] + sp;
            }
}

// ---------------------------------------------------------------------------
extern "C" void kernel_launch(void* const* d_in, const int* in_sizes, int n_in,
                              void* d_out, int out_size, void* d_ws, size_t ws_size,
                              hipStream_t stream) {
    const float* cur_pts  = (const float*)d_in[0];
    const float* cur_feat = (const float*)d_in[1];
    const float* nbr_pts  = (const float*)d_in[2];
    const float* nbr_feat = (const float*)d_in[3];
    const float* in_w     = (const float*)d_in[4];
    const float* in_b     = (const float*)d_in[5];
    const float* out_w    = (const float*)d_in[6];
    const float* out_b    = (const float*)d_in[7];
    const float* sw       = (const float*)d_in[8];
    const float* sb       = (const float*)d_in[9];

    char* ws = (char*)d_ws;
    bf16_t* w_in_b  = (bf16_t*)(ws + 0);          //  768*256*2 = 393216
    bf16_t* w_out_b = (bf16_t*)(ws + 393216);     //  256*256*2 = 131072
    int*    idx_buf = (int*)(ws + 524288);        //  6*2048*8*4 = 393216
    bf16_t* cur_edge = (bf16_t*)(ws + 917504);    //  4096*256*2 = 2097152
    bf16_t* all_nbr  = (bf16_t*)(ws + 3014656);   //  8192*256*2 = 4194304
    bf16_t* qp  = (bf16_t*)(ws + 7208960);        //  4096*256*2
    bf16_t* kp  = (bf16_t*)(ws + 9306112);        //  8192*256*2
    bf16_t* vpT = (bf16_t*)(ws + 13500416);       //  2*8*32*4096*2
    bf16_t* o_buf = (bf16_t*)(ws + 17694720);     //  4096*256*2 = 2097152
    bf16_t* Opart = (bf16_t*)(ws + 19791872);     //  4*2*2048*256*2 = 8388608
    float*  Lpart = (float*)(ws + 28180480);      //  4*2*8*2048*4 = 524288  (end 28704768)
    // vp (row-major V projection, 8192*256*2 = 4MB) aliases Opart: it is
    // fully consumed by vt_kernel before attn_kernel writes Opart.
    bf16_t* vp = (bf16_t*)(ws + 19791872);
    float* outp = (float*)d_out;

    wconv_kernel<<<dim3(768), dim3(256), 0, stream>>>(in_w, out_w, w_in_b, w_out_b);
    knn_kernel<<<dim3(128, 6), dim3(1024), 0, stream>>>(cur_pts, nbr_pts, idx_buf);
    edge_kernel<<<dim3(12288), dim3(64), 0, stream>>>(cur_feat, nbr_feat, idx_buf, cur_edge, all_nbr);
    qkv_kernel<<<dim3(4, 128, 3), dim3(256), 0, stream>>>(cur_edge, all_nbr, w_in_b, in_b, qp, kp, vp);
    vt_kernel<<<dim3(64, 16), dim3(256), 0, stream>>>(vp, vpT);
    attn_kernel<<<dim3(1024), dim3(256), 0, stream>>>(qp, kp, vpT, Opart, Lpart);
    attn_combine<<<dim3(512), dim3(256), 0, stream>>>(Opart, Lpart, o_buf);
    outproj_kernel<<<dim3(4, 64), dim3(256), 0, stream>>>(o_buf, w_out_b, out_b, cur_pts, sw, sb, outp);
}